// Round 1
// baseline (1501.649 us; speedup 1.0000x reference)
//
#include <hip/hip_runtime.h>
#include <math.h>

namespace {

constexpr int kBatch = 4;
constexpr int kN = 4096;
constexpr int kDim = 256;
constexpr int kHeads = 8;
constexpr int kHd = 32;
constexpr int kK = 16;
constexpr float kEps = 1e-8f;

// ---------------- LayerNorm (+ optional time_emb), one wave per row ----------------
template<bool ADD_TEMB>
__global__ __launch_bounds__(256) void ln_kernel(
    const float* __restrict__ x, const float* __restrict__ w,
    const float* __restrict__ bb, const float* __restrict__ temb,
    float* __restrict__ out) {
  int gt = blockIdx.x * 256 + threadIdx.x;
  int row = gt >> 6;            // one 64-lane wave per 256-elem row
  int lane = threadIdx.x & 63;
  const float4* xr = (const float4*)(x + (size_t)row * kDim);
  float4 v = xr[lane];
  float s = v.x + v.y + v.z + v.w;
  #pragma unroll
  for (int off = 32; off; off >>= 1) s += __shfl_xor(s, off);
  float mean = s * (1.0f / kDim);
  float dx = v.x - mean, dy = v.y - mean, dz = v.z - mean, dw = v.w - mean;
  float ss = dx * dx + dy * dy + dz * dz + dw * dw;
  #pragma unroll
  for (int off = 32; off; off >>= 1) ss += __shfl_xor(ss, off);
  float rstd = rsqrtf(ss * (1.0f / kDim) + 1e-5f);
  float4 wv = ((const float4*)w)[lane];
  float4 bv = ((const float4*)bb)[lane];
  float4 o;
  o.x = dx * rstd * wv.x + bv.x;
  o.y = dy * rstd * wv.y + bv.y;
  o.z = dz * rstd * wv.z + bv.z;
  o.w = dw * rstd * wv.w + bv.w;
  if (ADD_TEMB) {
    int bi = row >> 12;  // row / kN
    float4 t = ((const float4*)(temb + (size_t)bi * kDim))[lane];
    o.x += t.x; o.y += t.y; o.z += t.z; o.w += t.w;
  }
  ((float4*)(out + (size_t)row * kDim))[lane] = o;
}

__device__ inline float gelu_exact(float x) {
  return 0.5f * x * (1.0f + erff(x * 0.70710678118654752f));
}

// ---------------- f32 GEMM: C[M,N] = A[M,K] @ W[K,N] + bias, epilogues ----------------
// EPI: 0 = bias only, 1 = bias + residual R, 2 = gelu(bias + acc)
// BM=BN=64, BK=16, 256 threads, 4x4 per thread.
template<int EPI>
__global__ __launch_bounds__(256) void gemm_kernel(
    const float* __restrict__ A, const float* __restrict__ W,
    const float* __restrict__ bias, const float* __restrict__ R,
    float* __restrict__ C, int M, int N, int K) {
  __shared__ float As[16][64];
  __shared__ float Ws[16][64];
  int tid = threadIdx.x;
  int tx = tid & 15, ty = tid >> 4;
  int bm = blockIdx.x * 64, bn = blockIdx.y * 64;
  int arow = tid >> 2, acol = (tid & 3) * 4;
  int wrow = tid >> 4, wcol = (tid & 15) * 4;
  float acc[4][4] = {};
  for (int k0 = 0; k0 < K; k0 += 16) {
    float4 av = *(const float4*)(A + (size_t)(bm + arow) * K + k0 + acol);
    As[acol + 0][arow] = av.x;
    As[acol + 1][arow] = av.y;
    As[acol + 2][arow] = av.z;
    As[acol + 3][arow] = av.w;
    *(float4*)&Ws[wrow][wcol] =
        *(const float4*)(W + (size_t)(k0 + wrow) * N + bn + wcol);
    __syncthreads();
    #pragma unroll
    for (int kk = 0; kk < 16; ++kk) {
      float4 a = *(const float4*)&As[kk][ty * 4];
      float4 b = *(const float4*)&Ws[kk][tx * 4];
      float ar[4] = {a.x, a.y, a.z, a.w};
      float br[4] = {b.x, b.y, b.z, b.w};
      #pragma unroll
      for (int i = 0; i < 4; ++i)
        #pragma unroll
        for (int j = 0; j < 4; ++j)
          acc[i][j] = fmaf(ar[i], br[j], acc[i][j]);
    }
    __syncthreads();
  }
  #pragma unroll
  for (int i = 0; i < 4; ++i) {
    int row = bm + ty * 4 + i;
    #pragma unroll
    for (int j = 0; j < 4; ++j) {
      int col = bn + tx * 4 + j;
      float val = acc[i][j] + bias[col];
      if (EPI == 1) val += R[(size_t)row * N + col];
      if (EPI == 2) val = gelu_exact(val);
      C[(size_t)row * N + col] = val;
    }
  }
}

// ---------------- Poincare distance + top-K (smallest), one thread per row ----------------
// arccosh is monotonic -> select by arg = max(1 + num/(den+eps), 1); acosh only for the 16 kept.
// Scanning j ascending with strict < keeps lower indices on ties (matches lax.top_k).
__global__ __launch_bounds__(64) void topk_kernel(
    const float* __restrict__ pos, const float* __restrict__ cptr,
    int* __restrict__ idx_out, float* __restrict__ dist_out) {
  __shared__ float px[kN], py[kN], pz[kN], sq[kN];  // 64 KB
  int tid = threadIdx.x;
  int row = blockIdx.x * 64 + tid;   // flattened (b, i), blocks never straddle batches
  int b = row >> 12;
  const float* pb = pos + (size_t)b * kN * 3;
  for (int j = tid; j < kN; j += 64) {
    float x = pb[j * 3 + 0], y = pb[j * 3 + 1], z = pb[j * 3 + 2];
    px[j] = x; py[j] = y; pz[j] = z;
    sq[j] = x * x + y * y + z * z;
  }
  __syncthreads();
  float c = cptr[0];
  int i = row & (kN - 1);
  float xi = px[i], yi = py[i], zi = pz[i], sqi = sq[i];
  float oi = 1.0f - c * sqi;

  auto argf = [&](int j) {
    float dot = xi * px[j] + yi * py[j] + zi * pz[j];
    float d2 = sqi + sq[j] - 2.0f * dot;
    d2 = fmaxf(d2, 0.0f);
    float num = 2.0f * c * d2;
    float den = oi * (1.0f - c * sq[j]);
    float a = 1.0f + num / (den + kEps);
    return fmaxf(a, 1.0f);
  };

  float vals[kK];
  int idxs[kK];
  #pragma unroll
  for (int j = 0; j < kK; ++j) { vals[j] = argf(j); idxs[j] = j; }
  float kmax = vals[0]; int kslot = 0;
  #pragma unroll
  for (int s = 1; s < kK; ++s) if (vals[s] > kmax) { kmax = vals[s]; kslot = s; }

  for (int j = kK; j < kN; ++j) {
    float a = argf(j);
    if (a < kmax) {
      // static-index replacement (avoid scratch from runtime indexing)
      #pragma unroll
      for (int s = 0; s < kK; ++s) if (s == kslot) { vals[s] = a; idxs[s] = j; }
      kmax = vals[0]; kslot = 0;
      #pragma unroll
      for (int s = 1; s < kK; ++s) if (vals[s] > kmax) { kmax = vals[s]; kslot = s; }
    }
  }
  float rs = 1.0f / sqrtf(c);
  #pragma unroll
  for (int s = 0; s < kK; ++s) {
    idx_out[(size_t)row * kK + s] = idxs[s];
    dist_out[(size_t)row * kK + s] = acoshf(vals[s]) * rs;
  }
}

// ---------------- Gathered kNN attention, one thread per (b,n,h) ----------------
__global__ __launch_bounds__(256) void attn_kernel(
    const float* __restrict__ q, const float* __restrict__ k,
    const float* __restrict__ v, const int* __restrict__ nidx,
    const float* __restrict__ ndist, const float* __restrict__ log_tau,
    float* __restrict__ out) {
  int t = blockIdx.x * 256 + threadIdx.x;
  int h = t & (kHeads - 1);
  int row = t >> 3;      // (b, n)
  int b = row >> 12;
  float rtau = 1.0f / (expf(log_tau[0]) + kEps);
  const float4* qr = (const float4*)(q + (size_t)row * kDim + h * kHd);
  float4 qv[8];
  #pragma unroll
  for (int d = 0; d < 8; ++d) qv[d] = qr[d];

  int njs[kK];
  float sc[kK];
  const int* ir = nidx + (size_t)row * kK;
  const float* dr = ndist + (size_t)row * kK;
  float smax = -1e30f;
  #pragma unroll
  for (int j = 0; j < kK; ++j) {
    int nj = ir[j];
    njs[j] = nj;
    const float4* kr = (const float4*)(k + ((size_t)b * kN + nj) * kDim + h * kHd);
    float dot = 0.0f;
    #pragma unroll
    for (int d = 0; d < 8; ++d) {
      float4 kv = kr[d];
      dot = fmaf(qv[d].x, kv.x, dot);
      dot = fmaf(qv[d].y, kv.y, dot);
      dot = fmaf(qv[d].z, kv.z, dot);
      dot = fmaf(qv[d].w, kv.w, dot);
    }
    float s = dot * 0.17677669529663687f - dr[j] * rtau;  // 1/sqrt(32)
    sc[j] = s;
    smax = fmaxf(smax, s);
  }
  float sum = 0.0f;
  #pragma unroll
  for (int j = 0; j < kK; ++j) { sc[j] = expf(sc[j] - smax); sum += sc[j]; }
  float rsum = 1.0f / sum;
  float4 o[8];
  #pragma unroll
  for (int d = 0; d < 8; ++d) o[d] = make_float4(0.f, 0.f, 0.f, 0.f);
  #pragma unroll
  for (int j = 0; j < kK; ++j) {
    float p = sc[j] * rsum;
    const float4* vr = (const float4*)(v + ((size_t)b * kN + njs[j]) * kDim + h * kHd);
    #pragma unroll
    for (int d = 0; d < 8; ++d) {
      float4 vv = vr[d];
      o[d].x = fmaf(p, vv.x, o[d].x);
      o[d].y = fmaf(p, vv.y, o[d].y);
      o[d].z = fmaf(p, vv.z, o[d].z);
      o[d].w = fmaf(p, vv.w, o[d].w);
    }
  }
  float4* orow = (float4*)(out + (size_t)row * kDim + h * kHd);
  #pragma unroll
  for (int d = 0; d < 8; ++d) orow[d] = o[d];
}

}  // namespace

extern "C" void kernel_launch(void* const* d_in, const int* in_sizes, int n_in,
                              void* d_out, int out_size, void* d_ws, size_t ws_size,
                              hipStream_t stream) {
  const float* x    = (const float*)d_in[0];
  const float* pos  = (const float*)d_in[1];
  const float* c    = (const float*)d_in[2];
  const float* temb = (const float*)d_in[3];
  const float* Wq   = (const float*)d_in[4];
  const float* bq   = (const float*)d_in[5];
  const float* Wk   = (const float*)d_in[6];
  const float* bk   = (const float*)d_in[7];
  const float* Wv   = (const float*)d_in[8];
  const float* bv   = (const float*)d_in[9];
  const float* Wo   = (const float*)d_in[10];
  const float* bo   = (const float*)d_in[11];
  const float* W1   = (const float*)d_in[12];
  const float* b1   = (const float*)d_in[13];
  const float* W2   = (const float*)d_in[14];
  const float* b2   = (const float*)d_in[15];
  const float* ln1w = (const float*)d_in[16];
  const float* ln1b = (const float*)d_in[17];
  const float* ln2w = (const float*)d_in[18];
  const float* ln2b = (const float*)d_in[19];
  const float* ltau = (const float*)d_in[20];

  const int M = kBatch * kN;           // 16384
  constexpr size_t SZ = (size_t)16384 * 256;  // 4,194,304 floats per [M,256] buffer

  // Workspace layout (requires ~98 MB):
  float* ws   = (float*)d_ws;
  float* h    = ws;             // [M,256]  LN1 out; later reused as LN2 out
  float* qb   = ws + 1 * SZ;    // [M,256]
  float* kb   = ws + 2 * SZ;    // [M,256]
  float* vb   = ws + 3 * SZ;    // [M,256]
  float* attn = ws + 4 * SZ;    // [M,256]
  float* x2   = ws + 5 * SZ;    // [M,256]  persists to the end
  float* tln  = h;              // reuse (h dead after QKV GEMMs)
  float* g    = qb;             // [M,1024] reuses q,k,v,attn (exactly 4*SZ floats)
  int*   kidx = (int*)(ws + 6 * SZ);            // [M,16]
  float* kdst = ws + 6 * SZ + (size_t)M * kK;   // [M,16]

  // 1. h = LN1(x) + time_emb
  hipLaunchKernelGGL((ln_kernel<true>), dim3(4096), dim3(256), 0, stream,
                     x, ln1w, ln1b, temb, h);
  // 2. kNN over Poincare distances (independent of 1)
  hipLaunchKernelGGL(topk_kernel, dim3(256), dim3(64), 0, stream,
                     pos, c, kidx, kdst);
  // 3. Q, K, V
  hipLaunchKernelGGL((gemm_kernel<0>), dim3(256, 4), dim3(256), 0, stream,
                     h, Wq, bq, nullptr, qb, M, 256, 256);
  hipLaunchKernelGGL((gemm_kernel<0>), dim3(256, 4), dim3(256), 0, stream,
                     h, Wk, bk, nullptr, kb, M, 256, 256);
  hipLaunchKernelGGL((gemm_kernel<0>), dim3(256, 4), dim3(256), 0, stream,
                     h, Wv, bv, nullptr, vb, M, 256, 256);
  // 4. gathered attention
  hipLaunchKernelGGL(attn_kernel, dim3(512), dim3(256), 0, stream,
                     qb, kb, vb, kidx, kdst, ltau, attn);
  // 5. x2 = x + attn @ Wo + bo
  hipLaunchKernelGGL((gemm_kernel<1>), dim3(256, 4), dim3(256), 0, stream,
                     attn, Wo, bo, x, x2, M, 256, 256);
  // 6. tln = LN2(x2)
  hipLaunchKernelGGL((ln_kernel<false>), dim3(4096), dim3(256), 0, stream,
                     x2, ln2w, ln2b, nullptr, tln);
  // 7. g = gelu(tln @ W1 + b1)
  hipLaunchKernelGGL((gemm_kernel<2>), dim3(256, 16), dim3(256), 0, stream,
                     tln, W1, b1, nullptr, g, M, 1024, 256);
  // 8. out = x2 + g @ W2 + b2
  hipLaunchKernelGGL((gemm_kernel<1>), dim3(256, 4), dim3(256), 0, stream,
                     g, W2, b2, x2, (float*)d_out, M, 256, 1024);
}

// Round 2
// 768.757 us; speedup vs baseline: 1.9533x; 1.9533x over previous
//
#include <hip/hip_runtime.h>
#include <math.h>

namespace {

constexpr int kBatch = 4;
constexpr int kN = 4096;
constexpr int kDim = 256;
constexpr int kHeads = 8;
constexpr int kHd = 32;
constexpr int kK = 16;
constexpr float kEps = 1e-8f;

// ---------------- LayerNorm (+ optional time_emb), one wave per row ----------------
template<bool ADD_TEMB>
__global__ __launch_bounds__(256) void ln_kernel(
    const float* __restrict__ x, const float* __restrict__ w,
    const float* __restrict__ bb, const float* __restrict__ temb,
    float* __restrict__ out) {
  int gt = blockIdx.x * 256 + threadIdx.x;
  int row = gt >> 6;            // one 64-lane wave per 256-elem row
  int lane = threadIdx.x & 63;
  const float4* xr = (const float4*)(x + (size_t)row * kDim);
  float4 v = xr[lane];
  float s = v.x + v.y + v.z + v.w;
  #pragma unroll
  for (int off = 32; off; off >>= 1) s += __shfl_xor(s, off);
  float mean = s * (1.0f / kDim);
  float dx = v.x - mean, dy = v.y - mean, dz = v.z - mean, dw = v.w - mean;
  float ss = dx * dx + dy * dy + dz * dz + dw * dw;
  #pragma unroll
  for (int off = 32; off; off >>= 1) ss += __shfl_xor(ss, off);
  float rstd = rsqrtf(ss * (1.0f / kDim) + 1e-5f);
  float4 wv = ((const float4*)w)[lane];
  float4 bv = ((const float4*)bb)[lane];
  float4 o;
  o.x = dx * rstd * wv.x + bv.x;
  o.y = dy * rstd * wv.y + bv.y;
  o.z = dz * rstd * wv.z + bv.z;
  o.w = dw * rstd * wv.w + bv.w;
  if (ADD_TEMB) {
    int bi = row >> 12;  // row / kN
    float4 t = ((const float4*)(temb + (size_t)bi * kDim))[lane];
    o.x += t.x; o.y += t.y; o.z += t.z; o.w += t.w;
  }
  ((float4*)(out + (size_t)row * kDim))[lane] = o;
}

__device__ inline float gelu_exact(float x) {
  return 0.5f * x * (1.0f + erff(x * 0.70710678118654752f));
}

// ---------------- f32 GEMM: C[M,N] = A[M,K] @ W[K,N] + bias, epilogues ----------------
// EPI: 0 = bias only, 1 = bias + residual R, 2 = gelu(bias + acc)
// BM=BN=64, BK=16, 256 threads, 4x4 per thread.
template<int EPI>
__global__ __launch_bounds__(256) void gemm_kernel(
    const float* __restrict__ A, const float* __restrict__ W,
    const float* __restrict__ bias, const float* __restrict__ R,
    float* __restrict__ C, int M, int N, int K) {
  __shared__ float As[16][64];
  __shared__ float Ws[16][64];
  int tid = threadIdx.x;
  int tx = tid & 15, ty = tid >> 4;
  int bm = blockIdx.x * 64, bn = blockIdx.y * 64;
  int arow = tid >> 2, acol = (tid & 3) * 4;
  int wrow = tid >> 4, wcol = (tid & 15) * 4;
  float acc[4][4] = {};
  for (int k0 = 0; k0 < K; k0 += 16) {
    float4 av = *(const float4*)(A + (size_t)(bm + arow) * K + k0 + acol);
    As[acol + 0][arow] = av.x;
    As[acol + 1][arow] = av.y;
    As[acol + 2][arow] = av.z;
    As[acol + 3][arow] = av.w;
    *(float4*)&Ws[wrow][wcol] =
        *(const float4*)(W + (size_t)(k0 + wrow) * N + bn + wcol);
    __syncthreads();
    #pragma unroll
    for (int kk = 0; kk < 16; ++kk) {
      float4 a = *(const float4*)&As[kk][ty * 4];
      float4 b = *(const float4*)&Ws[kk][tx * 4];
      float ar[4] = {a.x, a.y, a.z, a.w};
      float br[4] = {b.x, b.y, b.z, b.w};
      #pragma unroll
      for (int i = 0; i < 4; ++i)
        #pragma unroll
        for (int j = 0; j < 4; ++j)
          acc[i][j] = fmaf(ar[i], br[j], acc[i][j]);
    }
    __syncthreads();
  }
  #pragma unroll
  for (int i = 0; i < 4; ++i) {
    int row = bm + ty * 4 + i;
    #pragma unroll
    for (int j = 0; j < 4; ++j) {
      int col = bn + tx * 4 + j;
      float val = acc[i][j] + bias[col];
      if (EPI == 1) val += R[(size_t)row * N + col];
      if (EPI == 2) val = gelu_exact(val);
      C[(size_t)row * N + col] = val;
    }
  }
}

// ---------------- Poincare distance + top-K, ONE WAVE PER ROW ----------------
// Selection key: r = num/(den+eps), monotone with arg = 1 + r (num already
// clamped >= 0, den > 0 since positions are inside the unit ball).
// Scan phase avoids division: accept iff num < kmax*den (den includes eps).
// 16 waves per 1024-thread block share one 64 KB staged position table.
__global__ __launch_bounds__(1024, 4) void topk_kernel(
    const float* __restrict__ pos, const float* __restrict__ cptr,
    int* __restrict__ idx_out, float* __restrict__ dist_out) {
  __shared__ float4 ps[kN];  // (x, y, z, c*|p|^2) — 64 KB
  int tid = threadIdx.x;
  int wave = tid >> 6, lane = tid & 63;
  int row = blockIdx.x * 16 + wave;   // 256 blocks/batch: never straddles batches
  int b = row >> 12;
  float c = cptr[0];
  const float* pb = pos + (size_t)b * kN * 3;
  for (int j = tid; j < kN; j += 1024) {
    float x = pb[j * 3 + 0], y = pb[j * 3 + 1], z = pb[j * 3 + 2];
    ps[j] = make_float4(x, y, z, c * (x * x + y * y + z * z));
  }
  __syncthreads();

  int i = row & (kN - 1);
  float4 pi = ps[i];
  float wi = pi.w;
  float oi = 1.0f - wi;                 // 1 - c*|p_i|^2
  float cx = c * pi.x, cy = c * pi.y, cz = c * pi.z;

  // num = 2*c*d2 = 2*max(wi + wj - 2*c*dot, 0); den = oi*(1 - wj) + eps
  auto numden = [&](int j, float& num, float& den) {
    float4 pj = ps[j];
    float cdot = cx * pj.x + cy * pj.y + cz * pj.z;
    float t = wi + pj.w - 2.0f * cdot;
    num = 2.0f * fmaxf(t, 0.0f);
    den = oi * (1.0f - pj.w) + kEps;
  };

  // Per-lane top-16 over this lane's 64 strided candidates.
  float vals[kK]; int idxs[kK];
  #pragma unroll
  for (int t = 0; t < kK; ++t) {
    int j = lane + t * 64;
    float num, den; numden(j, num, den);
    vals[t] = num / den; idxs[t] = j;
  }
  float kmax = vals[0]; int kslot = 0;
  #pragma unroll
  for (int s = 1; s < kK; ++s) if (vals[s] > kmax) { kmax = vals[s]; kslot = s; }

  for (int t = kK; t < 64; ++t) {
    int j = lane + t * 64;
    float num, den; numden(j, num, den);
    if (num < kmax * den) {           // r < kmax, division-free
      float r = num / den;
      #pragma unroll
      for (int s = 0; s < kK; ++s) if (s == kslot) { vals[s] = r; idxs[s] = j; }
      kmax = vals[0]; kslot = 0;
      #pragma unroll
      for (int s = 1; s < kK; ++s) if (vals[s] > kmax) { kmax = vals[s]; kslot = s; }
    }
  }

  // Merge 64 lanes x 16 -> global top-16 via 16 extraction rounds.
  float keep_r = 0.0f; int keep_i = 0;
  #pragma unroll
  for (int s = 0; s < kK; ++s) {
    float lmin = vals[0]; int lidx = idxs[0]; int lslot = 0;
    #pragma unroll
    for (int s2 = 1; s2 < kK; ++s2)
      if (vals[s2] < lmin || (vals[s2] == lmin && idxs[s2] < lidx)) {
        lmin = vals[s2]; lidx = idxs[s2]; lslot = s2;
      }
    float rv = lmin; int ri = lidx;
    #pragma unroll
    for (int off = 32; off; off >>= 1) {
      float ov = __shfl_xor(rv, off);
      int oi2 = __shfl_xor(ri, off);
      if (ov < rv || (ov == rv && oi2 < ri)) { rv = ov; ri = oi2; }
    }
    // exactly one lane owns (rv, ri): indices are disjoint across lanes
    if (lmin == rv && lidx == ri) {
      #pragma unroll
      for (int s2 = 0; s2 < kK; ++s2) if (s2 == lslot) vals[s2] = 3.0e38f;
    }
    if (lane == s) { keep_r = rv; keep_i = ri; }
  }

  if (lane < kK) {
    float rs = 1.0f / sqrtf(c);
    idx_out[(size_t)row * kK + lane] = keep_i;
    dist_out[(size_t)row * kK + lane] = acoshf(1.0f + keep_r) * rs;
  }
}

// ---------------- Gathered kNN attention, one thread per (b,n,h) ----------------
__global__ __launch_bounds__(256) void attn_kernel(
    const float* __restrict__ q, const float* __restrict__ k,
    const float* __restrict__ v, const int* __restrict__ nidx,
    const float* __restrict__ ndist, const float* __restrict__ log_tau,
    float* __restrict__ out) {
  int t = blockIdx.x * 256 + threadIdx.x;
  int h = t & (kHeads - 1);
  int row = t >> 3;      // (b, n)
  int b = row >> 12;
  float rtau = 1.0f / (expf(log_tau[0]) + kEps);
  const float4* qr = (const float4*)(q + (size_t)row * kDim + h * kHd);
  float4 qv[8];
  #pragma unroll
  for (int d = 0; d < 8; ++d) qv[d] = qr[d];

  int njs[kK];
  float sc[kK];
  const int* ir = nidx + (size_t)row * kK;
  const float* dr = ndist + (size_t)row * kK;
  float smax = -1e30f;
  #pragma unroll
  for (int j = 0; j < kK; ++j) {
    int nj = ir[j];
    njs[j] = nj;
    const float4* kr = (const float4*)(k + ((size_t)b * kN + nj) * kDim + h * kHd);
    float dot = 0.0f;
    #pragma unroll
    for (int d = 0; d < 8; ++d) {
      float4 kv = kr[d];
      dot = fmaf(qv[d].x, kv.x, dot);
      dot = fmaf(qv[d].y, kv.y, dot);
      dot = fmaf(qv[d].z, kv.z, dot);
      dot = fmaf(qv[d].w, kv.w, dot);
    }
    float s = dot * 0.17677669529663687f - dr[j] * rtau;  // 1/sqrt(32)
    sc[j] = s;
    smax = fmaxf(smax, s);
  }
  float sum = 0.0f;
  #pragma unroll
  for (int j = 0; j < kK; ++j) { sc[j] = expf(sc[j] - smax); sum += sc[j]; }
  float rsum = 1.0f / sum;
  float4 o[8];
  #pragma unroll
  for (int d = 0; d < 8; ++d) o[d] = make_float4(0.f, 0.f, 0.f, 0.f);
  #pragma unroll
  for (int j = 0; j < kK; ++j) {
    float p = sc[j] * rsum;
    const float4* vr = (const float4*)(v + ((size_t)b * kN + njs[j]) * kDim + h * kHd);
    #pragma unroll
    for (int d = 0; d < 8; ++d) {
      float4 vv = vr[d];
      o[d].x = fmaf(p, vv.x, o[d].x);
      o[d].y = fmaf(p, vv.y, o[d].y);
      o[d].z = fmaf(p, vv.z, o[d].z);
      o[d].w = fmaf(p, vv.w, o[d].w);
    }
  }
  float4* orow = (float4*)(out + (size_t)row * kDim + h * kHd);
  #pragma unroll
  for (int d = 0; d < 8; ++d) orow[d] = o[d];
}

}  // namespace

extern "C" void kernel_launch(void* const* d_in, const int* in_sizes, int n_in,
                              void* d_out, int out_size, void* d_ws, size_t ws_size,
                              hipStream_t stream) {
  const float* x    = (const float*)d_in[0];
  const float* pos  = (const float*)d_in[1];
  const float* c    = (const float*)d_in[2];
  const float* temb = (const float*)d_in[3];
  const float* Wq   = (const float*)d_in[4];
  const float* bq   = (const float*)d_in[5];
  const float* Wk   = (const float*)d_in[6];
  const float* bk   = (const float*)d_in[7];
  const float* Wv   = (const float*)d_in[8];
  const float* bv   = (const float*)d_in[9];
  const float* Wo   = (const float*)d_in[10];
  const float* bo   = (const float*)d_in[11];
  const float* W1   = (const float*)d_in[12];
  const float* b1   = (const float*)d_in[13];
  const float* W2   = (const float*)d_in[14];
  const float* b2   = (const float*)d_in[15];
  const float* ln1w = (const float*)d_in[16];
  const float* ln1b = (const float*)d_in[17];
  const float* ln2w = (const float*)d_in[18];
  const float* ln2b = (const float*)d_in[19];
  const float* ltau = (const float*)d_in[20];

  const int M = kBatch * kN;           // 16384
  constexpr size_t SZ = (size_t)16384 * 256;  // 4,194,304 floats per [M,256] buffer

  // Workspace layout (requires ~98 MB):
  float* ws   = (float*)d_ws;
  float* h    = ws;             // [M,256]  LN1 out; later reused as LN2 out
  float* qb   = ws + 1 * SZ;    // [M,256]
  float* kb   = ws + 2 * SZ;    // [M,256]
  float* vb   = ws + 3 * SZ;    // [M,256]
  float* attn = ws + 4 * SZ;    // [M,256]
  float* x2   = ws + 5 * SZ;    // [M,256]  persists to the end
  float* tln  = h;              // reuse (h dead after QKV GEMMs)
  float* g    = qb;             // [M,1024] reuses q,k,v,attn (exactly 4*SZ floats)
  int*   kidx = (int*)(ws + 6 * SZ);            // [M,16]
  float* kdst = ws + 6 * SZ + (size_t)M * kK;   // [M,16]

  // 1. h = LN1(x) + time_emb
  hipLaunchKernelGGL((ln_kernel<true>), dim3(4096), dim3(256), 0, stream,
                     x, ln1w, ln1b, temb, h);
  // 2. kNN over Poincare distances (independent of 1); one wave per row
  hipLaunchKernelGGL(topk_kernel, dim3(1024), dim3(1024), 0, stream,
                     pos, c, kidx, kdst);
  // 3. Q, K, V
  hipLaunchKernelGGL((gemm_kernel<0>), dim3(256, 4), dim3(256), 0, stream,
                     h, Wq, bq, nullptr, qb, M, 256, 256);
  hipLaunchKernelGGL((gemm_kernel<0>), dim3(256, 4), dim3(256), 0, stream,
                     h, Wk, bk, nullptr, kb, M, 256, 256);
  hipLaunchKernelGGL((gemm_kernel<0>), dim3(256, 4), dim3(256), 0, stream,
                     h, Wv, bv, nullptr, vb, M, 256, 256);
  // 4. gathered attention
  hipLaunchKernelGGL(attn_kernel, dim3(512), dim3(256), 0, stream,
                     qb, kb, vb, kidx, kdst, ltau, attn);
  // 5. x2 = x + attn @ Wo + bo
  hipLaunchKernelGGL((gemm_kernel<1>), dim3(256, 4), dim3(256), 0, stream,
                     attn, Wo, bo, x, x2, M, 256, 256);
  // 6. tln = LN2(x2)
  hipLaunchKernelGGL((ln_kernel<false>), dim3(4096), dim3(256), 0, stream,
                     x2, ln2w, ln2b, nullptr, tln);
  // 7. g = gelu(tln @ W1 + b1)
  hipLaunchKernelGGL((gemm_kernel<2>), dim3(256, 16), dim3(256), 0, stream,
                     tln, W1, b1, nullptr, g, M, 1024, 256);
  // 8. out = x2 + g @ W2 + b2
  hipLaunchKernelGGL((gemm_kernel<1>), dim3(256, 4), dim3(256), 0, stream,
                     g, W2, b2, x2, (float*)d_out, M, 256, 1024);
}

// Round 3
// 275.069 us; speedup vs baseline: 5.4592x; 2.7948x over previous
//
#include <hip/hip_runtime.h>
#include <math.h>

namespace {

constexpr int kBatch = 4;
constexpr int kN = 4096;
constexpr int kDim = 256;
constexpr int kHeads = 8;
constexpr int kK = 16;
constexpr float kEps = 1e-8f;

using u16 = unsigned short;
typedef __attribute__((ext_vector_type(8))) short short8;
typedef __attribute__((ext_vector_type(8))) u16 u16x8;
typedef __attribute__((ext_vector_type(4))) float f32x4;

__device__ __forceinline__ float b2f(u16 u) {
  union { unsigned int i; float f; } x; x.i = ((unsigned int)u) << 16; return x.f;
}
__device__ __forceinline__ u16 f2b(float f) {
  union { float f; unsigned int i; } x; x.f = f;
  unsigned int r = x.i + 0x7fffu + ((x.i >> 16) & 1u);  // RNE
  return (u16)(r >> 16);
}
__device__ __forceinline__ float gelu_exact(float x) {
  return 0.5f * x * (1.0f + erff(x * 0.70710678118654752f));
}
__device__ __forceinline__ void load_lds16(const u16* g, u16* l) {
  __builtin_amdgcn_global_load_lds(
      (const __attribute__((address_space(1))) unsigned int*)g,
      (__attribute__((address_space(3))) unsigned int*)l, 16, 0, 0);
}

// ---------------- LayerNorm (+ optional time_emb), one wave per row, bf16 out ----------------
template<bool ADD_TEMB>
__global__ __launch_bounds__(256) void ln_kernel(
    const float* __restrict__ x, const float* __restrict__ w,
    const float* __restrict__ bb, const float* __restrict__ temb,
    u16* __restrict__ out) {
  int gt = blockIdx.x * 256 + threadIdx.x;
  int row = gt >> 6;
  int lane = threadIdx.x & 63;
  const float4* xr = (const float4*)(x + (size_t)row * kDim);
  float4 v = xr[lane];
  float s = v.x + v.y + v.z + v.w;
  #pragma unroll
  for (int off = 32; off; off >>= 1) s += __shfl_xor(s, off);
  float mean = s * (1.0f / kDim);
  float dx = v.x - mean, dy = v.y - mean, dz = v.z - mean, dw = v.w - mean;
  float ss = dx * dx + dy * dy + dz * dz + dw * dw;
  #pragma unroll
  for (int off = 32; off; off >>= 1) ss += __shfl_xor(ss, off);
  float rstd = rsqrtf(ss * (1.0f / kDim) + 1e-5f);
  float4 wv = ((const float4*)w)[lane];
  float4 bv = ((const float4*)bb)[lane];
  float ox = dx * rstd * wv.x + bv.x;
  float oy = dy * rstd * wv.y + bv.y;
  float oz = dz * rstd * wv.z + bv.z;
  float ow = dw * rstd * wv.w + bv.w;
  if (ADD_TEMB) {
    int bi = row >> 12;
    float4 t = ((const float4*)(temb + (size_t)bi * kDim))[lane];
    ox += t.x; oy += t.y; oz += t.z; ow += t.w;
  }
  ushort4 ob;
  ob.x = f2b(ox); ob.y = f2b(oy); ob.z = f2b(oz); ob.w = f2b(ow);
  ((ushort4*)(out + (size_t)row * kDim))[lane] = ob;
}

// ---------------- Weight conversion: W[K][N] f32 -> Wt[N][K] bf16 ----------------
__global__ __launch_bounds__(256) void wconv4_kernel(
    const float* __restrict__ W0, const float* __restrict__ W1,
    const float* __restrict__ W2, const float* __restrict__ W3,
    u16* __restrict__ T0, u16* __restrict__ T1,
    u16* __restrict__ T2, u16* __restrict__ T3) {
  int idx = blockIdx.x * 256 + threadIdx.x;      // 4 * 65536
  int which = idx >> 16, e = idx & 65535;
  const float* W = which == 0 ? W0 : which == 1 ? W1 : which == 2 ? W2 : W3;
  u16* T = which == 0 ? T0 : which == 1 ? T1 : which == 2 ? T2 : T3;
  int n = e >> 8, kk = e & 255;
  T[e] = f2b(W[kk * 256 + n]);
}
template<int K, int N>
__global__ __launch_bounds__(256) void wconv_kernel(
    const float* __restrict__ W, u16* __restrict__ Wt) {
  int idx = blockIdx.x * 256 + threadIdx.x;      // K*N total
  int n = idx / K, kk = idx % K;                 // pow2 -> shifts
  Wt[idx] = f2b(W[(size_t)kk * N + n]);
}

// ---------------- bf16 MFMA GEMM core: C[M,N] = A[M,K] @ Bt[N,K]^T ----------------
// 128x128 tile, 4 waves (2x2), each wave 64x64 = 4x4 fragments of 16x16x32.
// EPI: 0 = bias -> bf16 out; 1 = bias + R(f32) -> f32 out; 2 = gelu(bias+acc) -> bf16 out
template<int EPI>
__device__ __forceinline__ void gemm_body(
    const u16* __restrict__ A, const u16* __restrict__ Bt,
    const float* __restrict__ bias, const float* __restrict__ R,
    float* __restrict__ Cf, u16* __restrict__ Cbf,
    int N, int K, int bx, int by) {
  __shared__ u16 Al[128 * 32];
  __shared__ u16 Bl[128 * 32];
  int tid = threadIdx.x;
  int wv = tid >> 6, ln = tid & 63;
  int wr = wv >> 1, wc = wv & 1;
  int lhi = ln >> 4, llo = ln & 15;
  int bm = bx * 128, bn = by * 128;

  f32x4 zero = {0.f, 0.f, 0.f, 0.f};
  f32x4 acc[4][4];
  #pragma unroll
  for (int mi = 0; mi < 4; ++mi)
    #pragma unroll
    for (int ni = 0; ni < 4; ++ni) acc[mi][ni] = zero;

  for (int k0 = 0; k0 < K; k0 += 32) {
    if (k0) __syncthreads();
    #pragma unroll
    for (int i = 0; i < 2; ++i) {
      int f = i * 256 + tid;
      int r = f >> 2, kp = f & 3;
      load_lds16(A + (size_t)(bm + r) * K + k0 + kp * 8,
                 &Al[(i * 256 + wv * 64) * 8]);
      load_lds16(Bt + (size_t)(bn + r) * K + k0 + kp * 8,
                 &Bl[(i * 256 + wv * 64) * 8]);
    }
    __syncthreads();
    short8 af[4], bf[4];
    #pragma unroll
    for (int mi = 0; mi < 4; ++mi)
      af[mi] = *(const short8*)&Al[(wr * 64 + mi * 16 + llo) * 32 + lhi * 8];
    #pragma unroll
    for (int ni = 0; ni < 4; ++ni)
      bf[ni] = *(const short8*)&Bl[(wc * 64 + ni * 16 + llo) * 32 + lhi * 8];
    #pragma unroll
    for (int mi = 0; mi < 4; ++mi)
      #pragma unroll
      for (int ni = 0; ni < 4; ++ni)
        acc[mi][ni] = __builtin_amdgcn_mfma_f32_16x16x32_bf16(
            af[mi], bf[ni], acc[mi][ni], 0, 0, 0);
  }

  // Epilogue. C/D layout: col = lane&15, row = (lane>>4)*4 + reg.
  #pragma unroll
  for (int mi = 0; mi < 4; ++mi) {
    #pragma unroll
    for (int r = 0; r < 4; ++r) {
      int row = bm + wr * 64 + mi * 16 + lhi * 4 + r;
      #pragma unroll
      for (int ni = 0; ni < 4; ++ni) {
        int col = bn + wc * 64 + ni * 16 + llo;
        float val = acc[mi][ni][r] + bias[col];
        if (EPI == 1) {
          val += R[(size_t)row * N + col];
          Cf[(size_t)row * N + col] = val;
        } else {
          if (EPI == 2) val = gelu_exact(val);
          Cbf[(size_t)row * N + col] = f2b(val);
        }
      }
    }
  }
}

template<int EPI>
__global__ __launch_bounds__(256) void gemm_kernel(
    const u16* __restrict__ A, const u16* __restrict__ Bt,
    const float* __restrict__ bias, const float* __restrict__ R,
    float* __restrict__ Cf, u16* __restrict__ Cbf, int N, int K) {
  gemm_body<EPI>(A, Bt, bias, R, Cf, Cbf, N, K, blockIdx.x, blockIdx.y);
}

__global__ __launch_bounds__(256) void qkv_kernel(
    const u16* __restrict__ A,
    const u16* __restrict__ Bq, const u16* __restrict__ Bk, const u16* __restrict__ Bv,
    const float* __restrict__ bq, const float* __restrict__ bk, const float* __restrict__ bv,
    u16* __restrict__ q, u16* __restrict__ k, u16* __restrict__ v) {
  int sel = blockIdx.y >> 1;
  const u16* Bt = sel == 0 ? Bq : sel == 1 ? Bk : Bv;
  const float* bias = sel == 0 ? bq : sel == 1 ? bk : bv;
  u16* C = sel == 0 ? q : sel == 1 ? k : v;
  gemm_body<0>(A, Bt, bias, nullptr, nullptr, C, 256, 256,
               blockIdx.x, blockIdx.y & 1);
}

// ---------------- Poincare top-K: wave-shared sorted top-16 + ballot filter ----------------
// Selection key r = num/(den+eps), monotone with the reference's arg = 1+r.
// Lanes 0..15 hold the sorted (ascending) running top-16; T = 16th value.
// Candidates pass the division-free test num < T*den; accepted ones are
// inserted (after equals -> stable, lower index first, matching lax.top_k).
__global__ __launch_bounds__(1024, 4) void topk_kernel(
    const float* __restrict__ pos, const float* __restrict__ cptr,
    int* __restrict__ idx_out, float* __restrict__ dist_out) {
  __shared__ float4 ps[kN];  // (x, y, z, c*|p|^2) — 64 KB
  int tid = threadIdx.x;
  int wave = tid >> 6, ln = tid & 63;
  int row = blockIdx.x * 16 + wave;   // blocks never straddle batches
  int b = row >> 12;
  float c = cptr[0];
  const float* pb = pos + (size_t)b * kN * 3;
  for (int j = tid; j < kN; j += 1024) {
    float x = pb[j * 3 + 0], y = pb[j * 3 + 1], z = pb[j * 3 + 2];
    ps[j] = make_float4(x, y, z, c * (x * x + y * y + z * z));
  }
  __syncthreads();

  int i = row & (kN - 1);
  float4 pi = ps[i];
  float wi = pi.w, oi = 1.0f - wi;
  float cx = c * pi.x, cy = c * pi.y, cz = c * pi.z;

  float lv = 3.0e38f;   // lanes 0..15: sorted list values; others scratch
  int li = 0;
  float T = 3.0e38f;    // current 16th-smallest (lane-uniform via shfl)

  for (int t = 0; t < 64; ++t) {
    int j = ln + t * 64;
    float4 pj = ps[j];
    float cdot = cx * pj.x + cy * pj.y + cz * pj.z;
    float tt = wi + pj.w - 2.0f * cdot;
    float num = 2.0f * fmaxf(tt, 0.0f);
    float den = oi * (1.0f - pj.w) + kEps;
    unsigned long long m = __ballot(num < T * den);
    while (m) {
      int src = __ffsll(m) - 1;
      m &= m - 1;
      float nnum = __shfl(num, src);
      float nden = __shfl(den, src);
      int nj = src + t * 64;
      float nv = nnum / nden;
      float pv = __shfl_up(lv, 1);
      int pidx = __shfl_up(li, 1);
      bool gt = lv > nv;
      bool take = gt && ((ln == 0) || (pv <= nv));
      lv = take ? nv : (gt ? pv : lv);
      li = take ? nj : (gt ? pidx : li);
      T = __shfl(lv, 15);
    }
  }
  if (ln < kK) {
    float rs = 1.0f / sqrtf(c);
    idx_out[(size_t)row * kK + ln] = li;
    dist_out[(size_t)row * kK + ln] = acoshf(1.0f + lv) * rs;
  }
}

// ---------------- Gathered kNN attention (bf16 q/k/v), one thread per (b,n,h) ----------------
__global__ __launch_bounds__(256) void attn_kernel(
    const u16* __restrict__ q, const u16* __restrict__ k,
    const u16* __restrict__ v, const int* __restrict__ nidx,
    const float* __restrict__ ndist, const float* __restrict__ log_tau,
    u16* __restrict__ out) {
  int t = blockIdx.x * 256 + threadIdx.x;
  int h = t & (kHeads - 1);
  int row = t >> 3;
  int b = row >> 12;
  float rtau = 1.0f / (expf(log_tau[0]) + kEps);
  const u16x8* qr = (const u16x8*)(q + (size_t)row * kDim + h * 32);
  float qf[32];
  #pragma unroll
  for (int cch = 0; cch < 4; ++cch) {
    u16x8 u = qr[cch];
    #pragma unroll
    for (int e = 0; e < 8; ++e) qf[cch * 8 + e] = b2f(u[e]);
  }

  int njs[kK];
  float sc[kK];
  const int* ir = nidx + (size_t)row * kK;
  const float* dr = ndist + (size_t)row * kK;
  float smax = -1e30f;
  #pragma unroll
  for (int j = 0; j < kK; ++j) {
    int nj = ir[j];
    njs[j] = nj;
    const u16x8* kr = (const u16x8*)(k + ((size_t)b * kN + nj) * kDim + h * 32);
    float dot = 0.0f;
    #pragma unroll
    for (int cch = 0; cch < 4; ++cch) {
      u16x8 u = kr[cch];
      #pragma unroll
      for (int e = 0; e < 8; ++e) dot = fmaf(qf[cch * 8 + e], b2f(u[e]), dot);
    }
    float s = dot * 0.17677669529663687f - dr[j] * rtau;  // 1/sqrt(32)
    sc[j] = s;
    smax = fmaxf(smax, s);
  }
  float sum = 0.0f;
  #pragma unroll
  for (int j = 0; j < kK; ++j) { sc[j] = expf(sc[j] - smax); sum += sc[j]; }
  float rsum = 1.0f / sum;
  float o[32];
  #pragma unroll
  for (int d = 0; d < 32; ++d) o[d] = 0.0f;
  #pragma unroll
  for (int j = 0; j < kK; ++j) {
    float p = sc[j] * rsum;
    const u16x8* vr = (const u16x8*)(v + ((size_t)b * kN + njs[j]) * kDim + h * 32);
    #pragma unroll
    for (int cch = 0; cch < 4; ++cch) {
      u16x8 u = vr[cch];
      #pragma unroll
      for (int e = 0; e < 8; ++e) o[cch * 8 + e] = fmaf(p, b2f(u[e]), o[cch * 8 + e]);
    }
  }
  u16x8* orow = (u16x8*)(out + (size_t)row * kDim + h * 32);
  #pragma unroll
  for (int cch = 0; cch < 4; ++cch) {
    u16x8 po;
    #pragma unroll
    for (int e = 0; e < 8; ++e) po[e] = f2b(o[cch * 8 + e]);
    orow[cch] = po;
  }
}

}  // namespace

extern "C" void kernel_launch(void* const* d_in, const int* in_sizes, int n_in,
                              void* d_out, int out_size, void* d_ws, size_t ws_size,
                              hipStream_t stream) {
  const float* x    = (const float*)d_in[0];
  const float* pos  = (const float*)d_in[1];
  const float* c    = (const float*)d_in[2];
  const float* temb = (const float*)d_in[3];
  const float* Wq   = (const float*)d_in[4];
  const float* bq   = (const float*)d_in[5];
  const float* Wk   = (const float*)d_in[6];
  const float* bk   = (const float*)d_in[7];
  const float* Wv   = (const float*)d_in[8];
  const float* bv   = (const float*)d_in[9];
  const float* Wo   = (const float*)d_in[10];
  const float* bo   = (const float*)d_in[11];
  const float* W1   = (const float*)d_in[12];
  const float* b1   = (const float*)d_in[13];
  const float* W2   = (const float*)d_in[14];
  const float* b2   = (const float*)d_in[15];
  const float* ln1w = (const float*)d_in[16];
  const float* ln1b = (const float*)d_in[17];
  const float* ln2w = (const float*)d_in[18];
  const float* ln2b = (const float*)d_in[19];
  const float* ltau = (const float*)d_in[20];

  const int M = kBatch * kN;                       // 16384
  const size_t MB = 1ull << 20;
  char* w = (char*)d_ws;
  u16*   h_bf  = (u16*)(w + 0 * MB);               // [M,256] bf16 (8 MB); reused as tln
  u16*   qb    = (u16*)(w + 8 * MB);
  u16*   kb    = (u16*)(w + 16 * MB);
  u16*   vb    = (u16*)(w + 24 * MB);
  u16*   attnb = (u16*)(w + 32 * MB);
  float* x2    = (float*)(w + 40 * MB);            // [M,256] f32 (16 MB)
  u16*   g_bf  = (u16*)(w + 56 * MB);              // [M,1024] bf16 (32 MB)
  u16*   wq_t  = (u16*)(w + 88 * MB);              // 128 KB each
  u16*   wk_t  = wq_t + 65536;
  u16*   wv_t  = wq_t + 2 * 65536;
  u16*   wo_t  = wq_t + 3 * 65536;
  u16*   w1_t  = (u16*)(w + 89 * MB);              // [1024][256] (512 KB)
  u16*   w2_t  = (u16*)(w + 89 * MB + 512 * 1024); // [256][1024] (512 KB)
  int*   kidx  = (int*)(w + 90 * MB);              // [M,16]
  float* kdst  = (float*)(w + 91 * MB);            // [M,16]
  u16*   tln   = h_bf;

  // 0. weight conversions (transposed bf16)
  hipLaunchKernelGGL(wconv4_kernel, dim3(1024), dim3(256), 0, stream,
                     Wq, Wk, Wv, Wo, wq_t, wk_t, wv_t, wo_t);
  hipLaunchKernelGGL((wconv_kernel<256, 1024>), dim3(1024), dim3(256), 0, stream,
                     W1, w1_t);
  hipLaunchKernelGGL((wconv_kernel<1024, 256>), dim3(1024), dim3(256), 0, stream,
                     W2, w2_t);
  // 1. h = LN1(x) + time_emb  (bf16)
  hipLaunchKernelGGL((ln_kernel<true>), dim3(4096), dim3(256), 0, stream,
                     x, ln1w, ln1b, temb, h_bf);
  // 2. kNN top-16 over Poincare distances
  hipLaunchKernelGGL(topk_kernel, dim3(1024), dim3(1024), 0, stream,
                     pos, c, kidx, kdst);
  // 3. fused Q,K,V MFMA GEMM
  hipLaunchKernelGGL(qkv_kernel, dim3(128, 6), dim3(256), 0, stream,
                     h_bf, wq_t, wk_t, wv_t, bq, bk, bv, qb, kb, vb);
  // 4. gathered attention (bf16 out)
  hipLaunchKernelGGL(attn_kernel, dim3(512), dim3(256), 0, stream,
                     qb, kb, vb, kidx, kdst, ltau, attnb);
  // 5. x2 = x + attn @ Wo + bo  (f32)
  hipLaunchKernelGGL((gemm_kernel<1>), dim3(128, 2), dim3(256), 0, stream,
                     attnb, wo_t, bo, x, x2, (u16*)nullptr, 256, 256);
  // 6. tln = LN2(x2)  (bf16)
  hipLaunchKernelGGL((ln_kernel<false>), dim3(4096), dim3(256), 0, stream,
                     x2, ln2w, ln2b, nullptr, tln);
  // 7. g = gelu(tln @ W1 + b1)  (bf16)
  hipLaunchKernelGGL((gemm_kernel<2>), dim3(128, 8), dim3(256), 0, stream,
                     tln, w1_t, b1, nullptr, (float*)nullptr, g_bf, 1024, 256);
  // 8. out = x2 + g @ W2 + b2  (f32)
  hipLaunchKernelGGL((gemm_kernel<1>), dim3(128, 2), dim3(256), 0, stream,
                     g_bf, w2_t, b2, x2, (float*)d_out, (u16*)nullptr, 256, 1024);
}

// Round 4
// 210.655 us; speedup vs baseline: 7.1285x; 1.3058x over previous
//
#include <hip/hip_runtime.h>
#include <math.h>

namespace {

constexpr int kBatch = 4;
constexpr int kN = 4096;
constexpr int kDim = 256;
constexpr int kHeads = 8;
constexpr int kK = 16;
constexpr float kEps = 1e-8f;

using u16 = unsigned short;
typedef __attribute__((ext_vector_type(8))) short short8;
typedef __attribute__((ext_vector_type(8))) u16 u16x8;
typedef __attribute__((ext_vector_type(4))) float f32x4;

__device__ __forceinline__ float b2f(u16 u) {
  union { unsigned int i; float f; } x; x.i = ((unsigned int)u) << 16; return x.f;
}
__device__ __forceinline__ u16 f2b(float f) {
  union { float f; unsigned int i; } x; x.f = f;
  unsigned int r = x.i + 0x7fffu + ((x.i >> 16) & 1u);  // RNE
  return (u16)(r >> 16);
}
__device__ __forceinline__ float gelu_exact(float x) {
  return 0.5f * x * (1.0f + erff(x * 0.70710678118654752f));
}
__device__ __forceinline__ void load_lds16(const u16* g, u16* l) {
  __builtin_amdgcn_global_load_lds(
      (const __attribute__((address_space(1))) unsigned int*)g,
      (__attribute__((address_space(3))) unsigned int*)l, 16, 0, 0);
}

// ---------------- LayerNorm (+ optional time_emb), one wave per row, bf16 out ----------------
template<bool ADD_TEMB>
__global__ __launch_bounds__(256) void ln_kernel(
    const float* __restrict__ x, const float* __restrict__ w,
    const float* __restrict__ bb, const float* __restrict__ temb,
    u16* __restrict__ out) {
  int gt = blockIdx.x * 256 + threadIdx.x;
  int row = gt >> 6;
  int lane = threadIdx.x & 63;
  const float4* xr = (const float4*)(x + (size_t)row * kDim);
  float4 v = xr[lane];
  float s = v.x + v.y + v.z + v.w;
  #pragma unroll
  for (int off = 32; off; off >>= 1) s += __shfl_xor(s, off);
  float mean = s * (1.0f / kDim);
  float dx = v.x - mean, dy = v.y - mean, dz = v.z - mean, dw = v.w - mean;
  float ss = dx * dx + dy * dy + dz * dz + dw * dw;
  #pragma unroll
  for (int off = 32; off; off >>= 1) ss += __shfl_xor(ss, off);
  float rstd = rsqrtf(ss * (1.0f / kDim) + 1e-5f);
  float4 wv = ((const float4*)w)[lane];
  float4 bv = ((const float4*)bb)[lane];
  float ox = dx * rstd * wv.x + bv.x;
  float oy = dy * rstd * wv.y + bv.y;
  float oz = dz * rstd * wv.z + bv.z;
  float ow = dw * rstd * wv.w + bv.w;
  if (ADD_TEMB) {
    int bi = row >> 12;
    float4 t = ((const float4*)(temb + (size_t)bi * kDim))[lane];
    ox += t.x; oy += t.y; oz += t.z; ow += t.w;
  }
  ushort4 ob;
  ob.x = f2b(ox); ob.y = f2b(oy); ob.z = f2b(oz); ob.w = f2b(ow);
  ((ushort4*)(out + (size_t)row * kDim))[lane] = ob;
}

// ---------------- Weight conversion: W[K][N] f32 -> Wt[N][K] bf16 ----------------
__global__ __launch_bounds__(256) void wconv4_kernel(
    const float* __restrict__ W0, const float* __restrict__ W1,
    const float* __restrict__ W2, const float* __restrict__ W3,
    u16* __restrict__ T0, u16* __restrict__ T1,
    u16* __restrict__ T2, u16* __restrict__ T3) {
  int idx = blockIdx.x * 256 + threadIdx.x;      // 4 * 65536
  int which = idx >> 16, e = idx & 65535;
  const float* W = which == 0 ? W0 : which == 1 ? W1 : which == 2 ? W2 : W3;
  u16* T = which == 0 ? T0 : which == 1 ? T1 : which == 2 ? T2 : T3;
  int n = e >> 8, kk = e & 255;
  T[e] = f2b(W[kk * 256 + n]);
}
template<int K, int N>
__global__ __launch_bounds__(256) void wconv_kernel(
    const float* __restrict__ W, u16* __restrict__ Wt) {
  int idx = blockIdx.x * 256 + threadIdx.x;      // K*N total
  int n = idx / K, kk = idx % K;                 // pow2 -> shifts
  Wt[idx] = f2b(W[(size_t)kk * N + n]);
}

// ---------------- bf16 MFMA GEMM core: C[M,N] = A[M,K] @ Bt[N,K]^T ----------------
// 128 x BN tile (BN in {64,128}), 4 waves (2x2); wave covers 64 x BN/2.
// EPI: 0 = bias -> bf16 out; 1 = bias + R(f32) -> f32 out; 2 = gelu(bias+acc) -> bf16 out
template<int EPI, int BN>
__device__ __forceinline__ void gemm_body(
    const u16* __restrict__ A, const u16* __restrict__ Bt,
    const float* __restrict__ bias, const float* __restrict__ R,
    float* __restrict__ Cf, u16* __restrict__ Cbf,
    int N, int K, int bx, int by) {
  constexpr int NI = BN / 32;          // B fragments per wave
  __shared__ u16 Al[128 * 32];
  __shared__ u16 Bl[BN * 32];
  int tid = threadIdx.x;
  int wv = tid >> 6, ln = tid & 63;
  int wr = wv >> 1, wc = wv & 1;
  int lhi = ln >> 4, llo = ln & 15;
  int bm = bx * 128, bn = by * BN;

  f32x4 zero = {0.f, 0.f, 0.f, 0.f};
  f32x4 acc[4][NI];
  #pragma unroll
  for (int mi = 0; mi < 4; ++mi)
    #pragma unroll
    for (int ni = 0; ni < NI; ++ni) acc[mi][ni] = zero;

  for (int k0 = 0; k0 < K; k0 += 32) {
    if (k0) __syncthreads();
    #pragma unroll
    for (int i = 0; i < 2; ++i) {
      int f = i * 256 + tid;
      int r = f >> 2, kp = f & 3;
      load_lds16(A + (size_t)(bm + r) * K + k0 + kp * 8,
                 &Al[(i * 256 + wv * 64) * 8]);
    }
    #pragma unroll
    for (int i = 0; i < BN / 64; ++i) {
      int f = i * 256 + tid;
      int r = f >> 2, kp = f & 3;
      load_lds16(Bt + (size_t)(bn + r) * K + k0 + kp * 8,
                 &Bl[(i * 256 + wv * 64) * 8]);
    }
    __syncthreads();
    short8 af[4], bf[NI];
    #pragma unroll
    for (int mi = 0; mi < 4; ++mi)
      af[mi] = *(const short8*)&Al[(wr * 64 + mi * 16 + llo) * 32 + lhi * 8];
    #pragma unroll
    for (int ni = 0; ni < NI; ++ni)
      bf[ni] = *(const short8*)&Bl[(wc * (BN / 2) + ni * 16 + llo) * 32 + lhi * 8];
    #pragma unroll
    for (int mi = 0; mi < 4; ++mi)
      #pragma unroll
      for (int ni = 0; ni < NI; ++ni)
        acc[mi][ni] = __builtin_amdgcn_mfma_f32_16x16x32_bf16(
            af[mi], bf[ni], acc[mi][ni], 0, 0, 0);
  }

  // Epilogue. C/D layout: col = lane&15, row = (lane>>4)*4 + reg.
  #pragma unroll
  for (int mi = 0; mi < 4; ++mi) {
    #pragma unroll
    for (int r = 0; r < 4; ++r) {
      int row = bm + wr * 64 + mi * 16 + lhi * 4 + r;
      #pragma unroll
      for (int ni = 0; ni < NI; ++ni) {
        int col = bn + wc * (BN / 2) + ni * 16 + llo;
        float val = acc[mi][ni][r] + bias[col];
        if (EPI == 1) {
          val += R[(size_t)row * N + col];
          Cf[(size_t)row * N + col] = val;
        } else {
          if (EPI == 2) val = gelu_exact(val);
          Cbf[(size_t)row * N + col] = f2b(val);
        }
      }
    }
  }
}

template<int EPI, int BN>
__global__ __launch_bounds__(256) void gemm_kernel(
    const u16* __restrict__ A, const u16* __restrict__ Bt,
    const float* __restrict__ bias, const float* __restrict__ R,
    float* __restrict__ Cf, u16* __restrict__ Cbf, int N, int K) {
  gemm_body<EPI, BN>(A, Bt, bias, R, Cf, Cbf, N, K, blockIdx.x, blockIdx.y);
}

__global__ __launch_bounds__(256) void qkv_kernel(
    const u16* __restrict__ A,
    const u16* __restrict__ Bq, const u16* __restrict__ Bk, const u16* __restrict__ Bv,
    const float* __restrict__ bq, const float* __restrict__ bk, const float* __restrict__ bv,
    u16* __restrict__ q, u16* __restrict__ k, u16* __restrict__ v) {
  int sel = blockIdx.y >> 1;
  const u16* Bt = sel == 0 ? Bq : sel == 1 ? Bk : Bv;
  const float* bias = sel == 0 ? bq : sel == 1 ? bk : bv;
  u16* C = sel == 0 ? q : sel == 1 ? k : v;
  gemm_body<0, 128>(A, Bt, bias, nullptr, nullptr, C, 256, 256,
                    blockIdx.x, blockIdx.y & 1);
}

// ---------------- Poincare top-K: bitonic bootstrap + deferred-T sorted insert ----------------
// Selection key r = num * rcp(den+eps), monotone with the reference's arg = 1+r.
// Lanes 0..15 hold the sorted (ascending) running top-16; T = 16th value.
// Bootstrap (candidates 0..63): full 64-lane bitonic sort by (r, idx).
// Main loop: ballot filter r < T; accepted lanes insert serially (ascending j ->
// stable, lower index first on ties, matching lax.top_k). T updates once per step;
// the sorted insert is self-guarding against stale T.
__global__ __launch_bounds__(1024, 4) void topk_kernel(
    const float* __restrict__ pos, const float* __restrict__ cptr,
    int* __restrict__ idx_out, float* __restrict__ dist_out) {
  __shared__ float4 ps[kN];  // (x, y, z, c*|p|^2) — 64 KB
  int tid = threadIdx.x;
  int wave = tid >> 6, ln = tid & 63;
  int row = blockIdx.x * 16 + wave;   // blocks never straddle batches
  int b = row >> 12;
  float c = cptr[0];
  const float* pb = pos + (size_t)b * kN * 3;
  for (int j = tid; j < kN; j += 1024) {
    float x = pb[j * 3 + 0], y = pb[j * 3 + 1], z = pb[j * 3 + 2];
    ps[j] = make_float4(x, y, z, c * (x * x + y * y + z * z));
  }
  __syncthreads();

  int i = row & (kN - 1);
  float4 pi = ps[i];
  float wi = pi.w, oi = 1.0f - wi;
  float cx = c * pi.x, cy = c * pi.y, cz = c * pi.z;

  auto keyf = [&](int j) {
    float4 pj = ps[j];
    float cdot = cx * pj.x + cy * pj.y + cz * pj.z;
    float tt = wi + pj.w - 2.0f * cdot;
    float num = 2.0f * fmaxf(tt, 0.0f);
    float den = oi * (1.0f - pj.w) + kEps;
    return num * __builtin_amdgcn_rcpf(den);
  };

  // ---- bootstrap: bitonic sort of candidates j = ln (0..63) by (r, idx) asc ----
  float lv = keyf(ln);
  int li = ln;
  #pragma unroll
  for (int kk = 2; kk <= 64; kk <<= 1) {
    #pragma unroll
    for (int jj = kk >> 1; jj >= 1; jj >>= 1) {
      float ov = __shfl_xor(lv, jj);
      int oidx = __shfl_xor(li, jj);
      bool less = (ov < lv) || (ov == lv && oidx < li);   // partner strictly smaller
      bool keepMin = (((ln & kk) == 0) == ((ln & jj) == 0));
      bool takePartner = keepMin ? less : !less;
      lv = takePartner ? ov : lv;
      li = takePartner ? oidx : li;
    }
  }
  float T = __shfl(lv, 15);

  // ---- main scan: candidates j = ln + t*64, t = 1..63 ----
  for (int t = 1; t < 64; ++t) {
    int j = ln + t * 64;
    float r = keyf(j);
    unsigned long long m = __ballot(r < T);
    if (m) {
      do {
        int src = __ffsll(m) - 1;
        m &= m - 1;
        float nv = __shfl(r, src);
        int nj = src + t * 64;          // wave-uniform
        float pv = __shfl_up(lv, 1);
        int pidx = __shfl_up(li, 1);
        bool gt = lv > nv;
        bool take = gt && ((ln == 0) || (pv <= nv));
        lv = take ? nv : (gt ? pv : lv);
        li = take ? nj : (gt ? pidx : li);
      } while (m);
      T = __shfl(lv, 15);
    }
  }
  if (ln < kK) {
    float rs = 1.0f / sqrtf(c);
    idx_out[(size_t)row * kK + ln] = li;
    dist_out[(size_t)row * kK + ln] = acoshf(1.0f + lv) * rs;
  }
}

// ---------------- Gathered kNN attention (bf16 q/k/v), one thread per (b,n,h) ----------------
__global__ __launch_bounds__(256) void attn_kernel(
    const u16* __restrict__ q, const u16* __restrict__ k,
    const u16* __restrict__ v, const int* __restrict__ nidx,
    const float* __restrict__ ndist, const float* __restrict__ log_tau,
    u16* __restrict__ out) {
  int t = blockIdx.x * 256 + threadIdx.x;
  int h = t & (kHeads - 1);
  int row = t >> 3;
  int b = row >> 12;
  float rtau = 1.0f / (expf(log_tau[0]) + kEps);
  const u16x8* qr = (const u16x8*)(q + (size_t)row * kDim + h * 32);
  float qf[32];
  #pragma unroll
  for (int cch = 0; cch < 4; ++cch) {
    u16x8 u = qr[cch];
    #pragma unroll
    for (int e = 0; e < 8; ++e) qf[cch * 8 + e] = b2f(u[e]);
  }

  int njs[kK];
  float sc[kK];
  const int* ir = nidx + (size_t)row * kK;
  const float* dr = ndist + (size_t)row * kK;
  float smax = -1e30f;
  #pragma unroll
  for (int j = 0; j < kK; ++j) {
    int nj = ir[j];
    njs[j] = nj;
    const u16x8* kr = (const u16x8*)(k + ((size_t)b * kN + nj) * kDim + h * 32);
    float dot = 0.0f;
    #pragma unroll
    for (int cch = 0; cch < 4; ++cch) {
      u16x8 u = kr[cch];
      #pragma unroll
      for (int e = 0; e < 8; ++e) dot = fmaf(qf[cch * 8 + e], b2f(u[e]), dot);
    }
    float s = dot * 0.17677669529663687f - dr[j] * rtau;  // 1/sqrt(32)
    sc[j] = s;
    smax = fmaxf(smax, s);
  }
  float sum = 0.0f;
  #pragma unroll
  for (int j = 0; j < kK; ++j) { sc[j] = expf(sc[j] - smax); sum += sc[j]; }
  float rsum = 1.0f / sum;
  float o[32];
  #pragma unroll
  for (int d = 0; d < 32; ++d) o[d] = 0.0f;
  #pragma unroll
  for (int j = 0; j < kK; ++j) {
    float p = sc[j] * rsum;
    const u16x8* vr = (const u16x8*)(v + ((size_t)b * kN + njs[j]) * kDim + h * 32);
    #pragma unroll
    for (int cch = 0; cch < 4; ++cch) {
      u16x8 u = vr[cch];
      #pragma unroll
      for (int e = 0; e < 8; ++e) o[cch * 8 + e] = fmaf(p, b2f(u[e]), o[cch * 8 + e]);
    }
  }
  u16x8* orow = (u16x8*)(out + (size_t)row * kDim + h * 32);
  #pragma unroll
  for (int cch = 0; cch < 4; ++cch) {
    u16x8 po;
    #pragma unroll
    for (int e = 0; e < 8; ++e) po[e] = f2b(o[cch * 8 + e]);
    orow[cch] = po;
  }
}

}  // namespace

extern "C" void kernel_launch(void* const* d_in, const int* in_sizes, int n_in,
                              void* d_out, int out_size, void* d_ws, size_t ws_size,
                              hipStream_t stream) {
  const float* x    = (const float*)d_in[0];
  const float* pos  = (const float*)d_in[1];
  const float* c    = (const float*)d_in[2];
  const float* temb = (const float*)d_in[3];
  const float* Wq   = (const float*)d_in[4];
  const float* bq   = (const float*)d_in[5];
  const float* Wk   = (const float*)d_in[6];
  const float* bk   = (const float*)d_in[7];
  const float* Wv   = (const float*)d_in[8];
  const float* bv   = (const float*)d_in[9];
  const float* Wo   = (const float*)d_in[10];
  const float* bo   = (const float*)d_in[11];
  const float* W1   = (const float*)d_in[12];
  const float* b1   = (const float*)d_in[13];
  const float* W2   = (const float*)d_in[14];
  const float* b2   = (const float*)d_in[15];
  const float* ln1w = (const float*)d_in[16];
  const float* ln1b = (const float*)d_in[17];
  const float* ln2w = (const float*)d_in[18];
  const float* ln2b = (const float*)d_in[19];
  const float* ltau = (const float*)d_in[20];

  const int M = kBatch * kN;                       // 16384
  const size_t MB = 1ull << 20;
  char* w = (char*)d_ws;
  u16*   h_bf  = (u16*)(w + 0 * MB);               // [M,256] bf16 (8 MB); reused as tln
  u16*   qb    = (u16*)(w + 8 * MB);
  u16*   kb    = (u16*)(w + 16 * MB);
  u16*   vb    = (u16*)(w + 24 * MB);
  u16*   attnb = (u16*)(w + 32 * MB);
  float* x2    = (float*)(w + 40 * MB);            // [M,256] f32 (16 MB)
  u16*   g_bf  = (u16*)(w + 56 * MB);              // [M,1024] bf16 (32 MB)
  u16*   wq_t  = (u16*)(w + 88 * MB);              // 128 KB each
  u16*   wk_t  = wq_t + 65536;
  u16*   wv_t  = wq_t + 2 * 65536;
  u16*   wo_t  = wq_t + 3 * 65536;
  u16*   w1_t  = (u16*)(w + 89 * MB);              // [1024][256] (512 KB)
  u16*   w2_t  = (u16*)(w + 89 * MB + 512 * 1024); // [256][1024] (512 KB)
  int*   kidx  = (int*)(w + 90 * MB);              // [M,16]
  float* kdst  = (float*)(w + 91 * MB);            // [M,16]
  u16*   tln   = h_bf;

  // 0. weight conversions (transposed bf16)
  hipLaunchKernelGGL(wconv4_kernel, dim3(1024), dim3(256), 0, stream,
                     Wq, Wk, Wv, Wo, wq_t, wk_t, wv_t, wo_t);
  hipLaunchKernelGGL((wconv_kernel<256, 1024>), dim3(1024), dim3(256), 0, stream,
                     W1, w1_t);
  hipLaunchKernelGGL((wconv_kernel<1024, 256>), dim3(1024), dim3(256), 0, stream,
                     W2, w2_t);
  // 1. h = LN1(x) + time_emb  (bf16)
  hipLaunchKernelGGL((ln_kernel<true>), dim3(4096), dim3(256), 0, stream,
                     x, ln1w, ln1b, temb, h_bf);
  // 2. kNN top-16 over Poincare distances
  hipLaunchKernelGGL(topk_kernel, dim3(1024), dim3(1024), 0, stream,
                     pos, c, kidx, kdst);
  // 3. fused Q,K,V MFMA GEMM
  hipLaunchKernelGGL(qkv_kernel, dim3(128, 6), dim3(256), 0, stream,
                     h_bf, wq_t, wk_t, wv_t, bq, bk, bv, qb, kb, vb);
  // 4. gathered attention (bf16 out)
  hipLaunchKernelGGL(attn_kernel, dim3(512), dim3(256), 0, stream,
                     qb, kb, vb, kidx, kdst, ltau, attnb);
  // 5. x2 = x + attn @ Wo + bo  (f32), 128x64 tiles -> 512 blocks (2/CU)
  hipLaunchKernelGGL((gemm_kernel<1, 64>), dim3(128, 4), dim3(256), 0, stream,
                     attnb, wo_t, bo, x, x2, (u16*)nullptr, 256, 256);
  // 6. tln = LN2(x2)  (bf16)
  hipLaunchKernelGGL((ln_kernel<false>), dim3(4096), dim3(256), 0, stream,
                     x2, ln2w, ln2b, nullptr, tln);
  // 7. g = gelu(tln @ W1 + b1)  (bf16)
  hipLaunchKernelGGL((gemm_kernel<2, 128>), dim3(128, 8), dim3(256), 0, stream,
                     tln, w1_t, b1, nullptr, (float*)nullptr, g_bf, 1024, 256);
  // 8. out = x2 + g @ W2 + b2  (f32), 128x64 tiles
  hipLaunchKernelGGL((gemm_kernel<1, 64>), dim3(128, 4), dim3(256), 0, stream,
                     g_bf, w2_t, b2, x2, (float*)d_out, (u16*)nullptr, 256, 1024);
}

// Round 5
// 189.963 us; speedup vs baseline: 7.9049x; 1.1089x over previous
//
#include <hip/hip_runtime.h>
#include <math.h>

namespace {

constexpr int kBatch = 4;
constexpr int kN = 4096;
constexpr int kDim = 256;
constexpr int kHeads = 8;
constexpr int kK = 16;
constexpr float kEps = 1e-8f;

using u16 = unsigned short;
typedef __attribute__((ext_vector_type(8))) short short8;
typedef __attribute__((ext_vector_type(8))) u16 u16x8;
typedef __attribute__((ext_vector_type(4))) float f32x4;

__device__ __forceinline__ float b2f(u16 u) {
  union { unsigned int i; float f; } x; x.i = ((unsigned int)u) << 16; return x.f;
}
__device__ __forceinline__ u16 f2b(float f) {
  union { float f; unsigned int i; } x; x.f = f;
  unsigned int r = x.i + 0x7fffu + ((x.i >> 16) & 1u);  // RNE
  return (u16)(r >> 16);
}
__device__ __forceinline__ float gelu_exact(float x) {
  return 0.5f * x * (1.0f + erff(x * 0.70710678118654752f));
}
__device__ __forceinline__ void load_lds16(const u16* g, u16* l) {
  __builtin_amdgcn_global_load_lds(
      (const __attribute__((address_space(1))) unsigned int*)g,
      (__attribute__((address_space(3))) unsigned int*)l, 16, 0, 0);
}

// ---------------- LayerNorm (+ optional time_emb), one wave per row, bf16 out ----------------
template<bool ADD_TEMB>
__global__ __launch_bounds__(256) void ln_kernel(
    const float* __restrict__ x, const float* __restrict__ w,
    const float* __restrict__ bb, const float* __restrict__ temb,
    u16* __restrict__ out) {
  int gt = blockIdx.x * 256 + threadIdx.x;
  int row = gt >> 6;
  int lane = threadIdx.x & 63;
  const float4* xr = (const float4*)(x + (size_t)row * kDim);
  float4 v = xr[lane];
  float s = v.x + v.y + v.z + v.w;
  #pragma unroll
  for (int off = 32; off; off >>= 1) s += __shfl_xor(s, off);
  float mean = s * (1.0f / kDim);
  float dx = v.x - mean, dy = v.y - mean, dz = v.z - mean, dw = v.w - mean;
  float ss = dx * dx + dy * dy + dz * dz + dw * dw;
  #pragma unroll
  for (int off = 32; off; off >>= 1) ss += __shfl_xor(ss, off);
  float rstd = rsqrtf(ss * (1.0f / kDim) + 1e-5f);
  float4 wv = ((const float4*)w)[lane];
  float4 bv = ((const float4*)bb)[lane];
  float ox = dx * rstd * wv.x + bv.x;
  float oy = dy * rstd * wv.y + bv.y;
  float oz = dz * rstd * wv.z + bv.z;
  float ow = dw * rstd * wv.w + bv.w;
  if (ADD_TEMB) {
    int bi = row >> 12;
    float4 t = ((const float4*)(temb + (size_t)bi * kDim))[lane];
    ox += t.x; oy += t.y; oz += t.z; ow += t.w;
  }
  ushort4 ob;
  ob.x = f2b(ox); ob.y = f2b(oy); ob.z = f2b(oz); ob.w = f2b(ow);
  ((ushort4*)(out + (size_t)row * kDim))[lane] = ob;
}

// ---------------- Weight conversion (all 6 weights, one kernel) ----------------
// Wt[n][k] = W[k][n] in bf16. Segments: [0,256K) four 256x256 mats; [256K,512K) W1; [512K,768K) W2.
__global__ __launch_bounds__(256) void wconv_all_kernel(
    const float* __restrict__ Wq, const float* __restrict__ Wk,
    const float* __restrict__ Wv, const float* __restrict__ Wo,
    const float* __restrict__ W1, const float* __restrict__ W2,
    u16* __restrict__ Tq, u16* __restrict__ Tk,
    u16* __restrict__ Tv, u16* __restrict__ To,
    u16* __restrict__ T1, u16* __restrict__ T2) {
  int idx = blockIdx.x * 256 + threadIdx.x;      // 3 * 262144 total
  int seg = idx >> 18;
  int e = idx & 262143;
  if (seg == 0) {
    int which = e >> 16, ee = e & 65535;
    const float* W = which == 0 ? Wq : which == 1 ? Wk : which == 2 ? Wv : Wo;
    u16* T = which == 0 ? Tq : which == 1 ? Tk : which == 2 ? Tv : To;
    int n = ee >> 8, kk = ee & 255;
    T[ee] = f2b(W[kk * 256 + n]);
  } else if (seg == 1) {           // W1[256][1024] -> T1[1024][256]
    int n = e >> 8, kk = e & 255;
    T1[e] = f2b(W1[kk * 1024 + n]);
  } else {                         // W2[1024][256] -> T2[256][1024]
    int n = e >> 10, kk = e & 1023;
    T2[e] = f2b(W2[kk * 256 + n]);
  }
}

// ---------------- bf16 MFMA GEMM core: C[M,N] = A[M,K] @ Bt[N,K]^T ----------------
// 128 x BN tile (BN in {64,128}), 4 waves (2x2); wave covers 64 x BN/2.
// EPI: 0 = bias -> bf16 out; 1 = bias + R(f32) -> f32 out; 2 = gelu(bias+acc) -> bf16 out
template<int EPI, int BN>
__device__ __forceinline__ void gemm_body(
    const u16* __restrict__ A, const u16* __restrict__ Bt,
    const float* __restrict__ bias, const float* __restrict__ R,
    float* __restrict__ Cf, u16* __restrict__ Cbf,
    int N, int K, int bx, int by) {
  constexpr int NI = BN / 32;          // B fragments per wave
  __shared__ u16 Al[128 * 32];
  __shared__ u16 Bl[BN * 32];
  int tid = threadIdx.x;
  int wv = tid >> 6, ln = tid & 63;
  int wr = wv >> 1, wc = wv & 1;
  int lhi = ln >> 4, llo = ln & 15;
  int bm = bx * 128, bn = by * BN;

  f32x4 zero = {0.f, 0.f, 0.f, 0.f};
  f32x4 acc[4][NI];
  #pragma unroll
  for (int mi = 0; mi < 4; ++mi)
    #pragma unroll
    for (int ni = 0; ni < NI; ++ni) acc[mi][ni] = zero;

  for (int k0 = 0; k0 < K; k0 += 32) {
    if (k0) __syncthreads();
    #pragma unroll
    for (int i = 0; i < 2; ++i) {
      int f = i * 256 + tid;
      int r = f >> 2, kp = f & 3;
      load_lds16(A + (size_t)(bm + r) * K + k0 + kp * 8,
                 &Al[(i * 256 + wv * 64) * 8]);
    }
    #pragma unroll
    for (int i = 0; i < BN / 64; ++i) {
      int f = i * 256 + tid;
      int r = f >> 2, kp = f & 3;
      load_lds16(Bt + (size_t)(bn + r) * K + k0 + kp * 8,
                 &Bl[(i * 256 + wv * 64) * 8]);
    }
    __syncthreads();
    short8 af[4], bf[NI];
    #pragma unroll
    for (int mi = 0; mi < 4; ++mi)
      af[mi] = *(const short8*)&Al[(wr * 64 + mi * 16 + llo) * 32 + lhi * 8];
    #pragma unroll
    for (int ni = 0; ni < NI; ++ni)
      bf[ni] = *(const short8*)&Bl[(wc * (BN / 2) + ni * 16 + llo) * 32 + lhi * 8];
    #pragma unroll
    for (int mi = 0; mi < 4; ++mi)
      #pragma unroll
      for (int ni = 0; ni < NI; ++ni)
        acc[mi][ni] = __builtin_amdgcn_mfma_f32_16x16x32_bf16(
            af[mi], bf[ni], acc[mi][ni], 0, 0, 0);
  }

  // Epilogue. C/D layout: col = lane&15, row = (lane>>4)*4 + reg.
  #pragma unroll
  for (int mi = 0; mi < 4; ++mi) {
    #pragma unroll
    for (int r = 0; r < 4; ++r) {
      int row = bm + wr * 64 + mi * 16 + lhi * 4 + r;
      #pragma unroll
      for (int ni = 0; ni < NI; ++ni) {
        int col = bn + wc * (BN / 2) + ni * 16 + llo;
        float val = acc[mi][ni][r] + bias[col];
        if (EPI == 1) {
          val += R[(size_t)row * N + col];
          Cf[(size_t)row * N + col] = val;
        } else {
          if (EPI == 2) val = gelu_exact(val);
          Cbf[(size_t)row * N + col] = f2b(val);
        }
      }
    }
  }
}

template<int EPI, int BN>
__global__ __launch_bounds__(256) void gemm_kernel(
    const u16* __restrict__ A, const u16* __restrict__ Bt,
    const float* __restrict__ bias, const float* __restrict__ R,
    float* __restrict__ Cf, u16* __restrict__ Cbf, int N, int K) {
  gemm_body<EPI, BN>(A, Bt, bias, R, Cf, Cbf, N, K, blockIdx.x, blockIdx.y);
}

__global__ __launch_bounds__(256) void qkv_kernel(
    const u16* __restrict__ A,
    const u16* __restrict__ Bq, const u16* __restrict__ Bk, const u16* __restrict__ Bv,
    const float* __restrict__ bq, const float* __restrict__ bk, const float* __restrict__ bv,
    u16* __restrict__ q, u16* __restrict__ k, u16* __restrict__ v) {
  int sel = blockIdx.y >> 1;
  const u16* Bt = sel == 0 ? Bq : sel == 1 ? Bk : Bv;
  const float* bias = sel == 0 ? bq : sel == 1 ? bk : bv;
  u16* C = sel == 0 ? q : sel == 1 ? k : v;
  gemm_body<0, 128>(A, Bt, bias, nullptr, nullptr, C, 256, 256,
                    blockIdx.x, blockIdx.y & 1);
}

// ---------------- Poincare top-K: packed-key selection, DS-free insert loop ----------------
// Selection key r = num * rcp(den+eps) (monotone with reference's arg = 1+r), packed as
// pk = (bits(r) & 0xFFFFF000) | j  -> lexicographic (r-truncated, j): matches lax.top_k's
// lower-index-on-tie. Lanes 0..15 hold the sorted running top-16 (ascending u32).
// Bootstrap: 64-lane bitonic sort of candidates 0..63. Main loop: ballot filter
// pk < T; inserts use readlane (VALU) + DPP row_shr:1 (VALU) -- no DS ops.
// Exact distances recomputed at the end from the winning indices.
__global__ __launch_bounds__(1024, 4) void topk_kernel(
    const float* __restrict__ pos, const float* __restrict__ cptr,
    int* __restrict__ idx_out, float* __restrict__ dist_out) {
  __shared__ float4 ps[kN];  // (x, y, z, c*|p|^2) — 64 KB
  int tid = threadIdx.x;
  int wave = tid >> 6, ln = tid & 63;
  int row = blockIdx.x * 16 + wave;   // blocks never straddle batches
  int b = row >> 12;
  float c = cptr[0];
  const float4* pbv = (const float4*)(pos + (size_t)b * kN * 3);
  {
    int q = tid;  // 1024 threads, each stages 4 positions (3 coalesced float4)
    float4 f0 = pbv[q * 3 + 0], f1 = pbv[q * 3 + 1], f2 = pbv[q * 3 + 2];
    float xs[4] = {f0.x, f0.w, f1.z, f2.y};
    float ys[4] = {f0.y, f1.x, f1.w, f2.z};
    float zs[4] = {f0.z, f1.y, f2.x, f2.w};
    #pragma unroll
    for (int e = 0; e < 4; ++e)
      ps[q * 4 + e] = make_float4(xs[e], ys[e], zs[e],
          c * (xs[e] * xs[e] + ys[e] * ys[e] + zs[e] * zs[e]));
  }
  __syncthreads();

  int i = row & (kN - 1);
  float4 pi = ps[i];
  float wi = pi.w, oi = 1.0f - wi;
  float sx = 2.0f * c * pi.x, sy = 2.0f * c * pi.y, sz = 2.0f * c * pi.z;

  auto pkey = [&](int j) -> unsigned {
    float4 pj = ps[j];
    float tt = wi + pj.w;
    tt = fmaf(-sx, pj.x, tt);
    tt = fmaf(-sy, pj.y, tt);
    tt = fmaf(-sz, pj.z, tt);
    float num = 2.0f * fmaxf(tt, 0.0f);
    float den = fmaf(-oi, pj.w, oi) + kEps;   // oi*(1-pj.w) + eps
    float r = num * __builtin_amdgcn_rcpf(den);
    union { float f; unsigned u; } cv; cv.f = r;
    return (cv.u & 0xFFFFF000u) | (unsigned)j;
  };

  // ---- bootstrap: bitonic sort of candidates j = ln (0..63), ascending u32 ----
  unsigned lpk = pkey(ln);
  #pragma unroll
  for (int kk = 2; kk <= 64; kk <<= 1) {
    #pragma unroll
    for (int jj = kk >> 1; jj >= 1; jj >>= 1) {
      unsigned ov = (unsigned)__shfl_xor((int)lpk, jj);
      bool keepMin = (((ln & kk) == 0) == ((ln & jj) == 0));
      bool less = ov < lpk;
      if (keepMin ? less : !less) lpk = ov;
    }
  }
  unsigned T = (unsigned)__builtin_amdgcn_readlane((int)lpk, 15);

  // ---- main scan: candidates j = ln + t*64, t = 1..63 ----
  for (int t = 1; t < 64; ++t) {
    unsigned cpk = pkey(ln + t * 64);
    unsigned long long m = __ballot(cpk < T);
    if (m) {
      do {
        int src = __ffsll(m) - 1;
        m &= m - 1;
        unsigned npk = (unsigned)__builtin_amdgcn_readlane((int)cpk, src);
        unsigned pv = (unsigned)__builtin_amdgcn_update_dpp(
            0, (int)lpk, 0x111 /*row_shr:1*/, 0xF, 0xF, false);
        bool gt = lpk > npk;
        bool take = gt && ((ln == 0) || (pv <= npk));
        lpk = take ? npk : (gt ? pv : lpk);
      } while (m);
      T = (unsigned)__builtin_amdgcn_readlane((int)lpk, 15);
    }
  }

  if (ln < kK) {
    int j = (int)(lpk & 0xFFFu);
    // exact recompute (full-precision divide), matching the reference formula
    float4 pj = ps[j];
    float tt = wi + pj.w;
    tt = fmaf(-sx, pj.x, tt);
    tt = fmaf(-sy, pj.y, tt);
    tt = fmaf(-sz, pj.z, tt);
    float num = 2.0f * fmaxf(tt, 0.0f);
    float den = fmaf(-oi, pj.w, oi) + kEps;
    float arg = fmaxf(1.0f + num / den, 1.0f);
    float rs = 1.0f / sqrtf(c);
    idx_out[(size_t)row * kK + ln] = j;
    dist_out[(size_t)row * kK + ln] = acoshf(arg) * rs;
  }
}

// ---------------- Gathered kNN attention (bf16 q/k/v), one thread per (b,n,h) ----------------
__global__ __launch_bounds__(256) void attn_kernel(
    const u16* __restrict__ q, const u16* __restrict__ k,
    const u16* __restrict__ v, const int* __restrict__ nidx,
    const float* __restrict__ ndist, const float* __restrict__ log_tau,
    u16* __restrict__ out) {
  int t = blockIdx.x * 256 + threadIdx.x;
  int h = t & (kHeads - 1);
  int row = t >> 3;
  int b = row >> 12;
  float rtau = 1.0f / (expf(log_tau[0]) + kEps);
  const u16x8* qr = (const u16x8*)(q + (size_t)row * kDim + h * 32);
  float qf[32];
  #pragma unroll
  for (int cch = 0; cch < 4; ++cch) {
    u16x8 u = qr[cch];
    #pragma unroll
    for (int e = 0; e < 8; ++e) qf[cch * 8 + e] = b2f(u[e]);
  }

  int njs[kK];
  float sc[kK];
  const int* ir = nidx + (size_t)row * kK;
  const float* dr = ndist + (size_t)row * kK;
  float smax = -1e30f;
  #pragma unroll
  for (int j = 0; j < kK; ++j) {
    int nj = ir[j];
    njs[j] = nj;
    const u16x8* kr = (const u16x8*)(k + ((size_t)b * kN + nj) * kDim + h * 32);
    float dot = 0.0f;
    #pragma unroll
    for (int cch = 0; cch < 4; ++cch) {
      u16x8 u = kr[cch];
      #pragma unroll
      for (int e = 0; e < 8; ++e) dot = fmaf(qf[cch * 8 + e], b2f(u[e]), dot);
    }
    float s = dot * 0.17677669529663687f - dr[j] * rtau;  // 1/sqrt(32)
    sc[j] = s;
    smax = fmaxf(smax, s);
  }
  float sum = 0.0f;
  #pragma unroll
  for (int j = 0; j < kK; ++j) { sc[j] = expf(sc[j] - smax); sum += sc[j]; }
  float rsum = 1.0f / sum;
  float o[32];
  #pragma unroll
  for (int d = 0; d < 32; ++d) o[d] = 0.0f;
  #pragma unroll
  for (int j = 0; j < kK; ++j) {
    float p = sc[j] * rsum;
    const u16x8* vr = (const u16x8*)(v + ((size_t)b * kN + njs[j]) * kDim + h * 32);
    #pragma unroll
    for (int cch = 0; cch < 4; ++cch) {
      u16x8 u = vr[cch];
      #pragma unroll
      for (int e = 0; e < 8; ++e) o[cch * 8 + e] = fmaf(p, b2f(u[e]), o[cch * 8 + e]);
    }
  }
  u16x8* orow = (u16x8*)(out + (size_t)row * kDim + h * 32);
  #pragma unroll
  for (int cch = 0; cch < 4; ++cch) {
    u16x8 po;
    #pragma unroll
    for (int e = 0; e < 8; ++e) po[e] = f2b(o[cch * 8 + e]);
    orow[cch] = po;
  }
}

}  // namespace

extern "C" void kernel_launch(void* const* d_in, const int* in_sizes, int n_in,
                              void* d_out, int out_size, void* d_ws, size_t ws_size,
                              hipStream_t stream) {
  const float* x    = (const float*)d_in[0];
  const float* pos  = (const float*)d_in[1];
  const float* c    = (const float*)d_in[2];
  const float* temb = (const float*)d_in[3];
  const float* Wq   = (const float*)d_in[4];
  const float* bq   = (const float*)d_in[5];
  const float* Wk   = (const float*)d_in[6];
  const float* bk   = (const float*)d_in[7];
  const float* Wv   = (const float*)d_in[8];
  const float* bv   = (const float*)d_in[9];
  const float* Wo   = (const float*)d_in[10];
  const float* bo   = (const float*)d_in[11];
  const float* W1   = (const float*)d_in[12];
  const float* b1   = (const float*)d_in[13];
  const float* W2   = (const float*)d_in[14];
  const float* b2   = (const float*)d_in[15];
  const float* ln1w = (const float*)d_in[16];
  const float* ln1b = (const float*)d_in[17];
  const float* ln2w = (const float*)d_in[18];
  const float* ln2b = (const float*)d_in[19];
  const float* ltau = (const float*)d_in[20];

  const size_t MB = 1ull << 20;
  char* w = (char*)d_ws;
  u16*   h_bf  = (u16*)(w + 0 * MB);               // [M,256] bf16 (8 MB); reused as tln
  u16*   qb    = (u16*)(w + 8 * MB);
  u16*   kb    = (u16*)(w + 16 * MB);
  u16*   vb    = (u16*)(w + 24 * MB);
  u16*   attnb = (u16*)(w + 32 * MB);
  float* x2    = (float*)(w + 40 * MB);            // [M,256] f32 (16 MB)
  u16*   g_bf  = (u16*)(w + 56 * MB);              // [M,1024] bf16 (32 MB)
  u16*   wq_t  = (u16*)(w + 88 * MB);              // 128 KB each
  u16*   wk_t  = wq_t + 65536;
  u16*   wv_t  = wq_t + 2 * 65536;
  u16*   wo_t  = wq_t + 3 * 65536;
  u16*   w1_t  = (u16*)(w + 89 * MB);              // [1024][256] (512 KB)
  u16*   w2_t  = (u16*)(w + 89 * MB + 512 * 1024); // [256][1024] (512 KB)
  int*   kidx  = (int*)(w + 90 * MB);              // [M,16]
  float* kdst  = (float*)(w + 91 * MB);            // [M,16]
  u16*   tln   = h_bf;

  // 0. weight conversions (all six, one kernel)
  hipLaunchKernelGGL(wconv_all_kernel, dim3(3072), dim3(256), 0, stream,
                     Wq, Wk, Wv, Wo, W1, W2, wq_t, wk_t, wv_t, wo_t, w1_t, w2_t);
  // 1. h = LN1(x) + time_emb  (bf16)
  hipLaunchKernelGGL((ln_kernel<true>), dim3(4096), dim3(256), 0, stream,
                     x, ln1w, ln1b, temb, h_bf);
  // 2. kNN top-16 over Poincare distances
  hipLaunchKernelGGL(topk_kernel, dim3(1024), dim3(1024), 0, stream,
                     pos, c, kidx, kdst);
  // 3. fused Q,K,V MFMA GEMM
  hipLaunchKernelGGL(qkv_kernel, dim3(128, 6), dim3(256), 0, stream,
                     h_bf, wq_t, wk_t, wv_t, bq, bk, bv, qb, kb, vb);
  // 4. gathered attention (bf16 out)
  hipLaunchKernelGGL(attn_kernel, dim3(512), dim3(256), 0, stream,
                     qb, kb, vb, kidx, kdst, ltau, attnb);
  // 5. x2 = x + attn @ Wo + bo  (f32), 128x64 tiles -> 512 blocks (2/CU)
  hipLaunchKernelGGL((gemm_kernel<1, 64>), dim3(128, 4), dim3(256), 0, stream,
                     attnb, wo_t, bo, x, x2, (u16*)nullptr, 256, 256);
  // 6. tln = LN2(x2)  (bf16)
  hipLaunchKernelGGL((ln_kernel<false>), dim3(4096), dim3(256), 0, stream,
                     x2, ln2w, ln2b, nullptr, tln);
  // 7. g = gelu(tln @ W1 + b1)  (bf16)
  hipLaunchKernelGGL((gemm_kernel<2, 128>), dim3(128, 8), dim3(256), 0, stream,
                     tln, w1_t, b1, nullptr, (float*)nullptr, g_bf, 1024, 256);
  // 8. out = x2 + g @ W2 + b2  (f32), 128x64 tiles
  hipLaunchKernelGGL((gemm_kernel<1, 64>), dim3(128, 4), dim3(256), 0, stream,
                     g_bf, w2_t, b2, x2, (float*)d_out, (u16*)nullptr, 256, 1024);
}